// Round 6
// baseline (351.608 us; speedup 1.0000x reference)
//
#include <hip/hip_runtime.h>
#include <cstdint>

#define T_LEN 1024
#define V_DIM 512
#define S_LEN 128
#define NEG2  (-1.0e30f)
#define PREP_BLOCKS 2048  // grid-stride prep
#define ROWS_PER_WAVE 8   // 65536 rows / (2048 blk * 4 waves)
#define WPB   16          // alpha waves per block: 4 waves/SIMD -> 4x TLP
#define ALPHA_BLOCKS 4    // 64 batches / 16 waves

// Staging: LINEAR probabilities of the needed classes per (b,t).
__device__ float2 g_plab[(size_t)64 * T_LEN * 64 + 64];  // 32 MiB: labels 2l,2l+1 per lane
__device__ float  g_pblank[(size_t)64 * T_LEN + 64];     // 256 KiB: blank (+pad for overread)

// whole-wave shift-down-by-1 via DPP wave_shr1: lane l <- lane l-1, lane 0 <- 0.
static __device__ __forceinline__ float dpp_shr1_f(float x) {
    return __int_as_float(__builtin_amdgcn_update_dpp(
        0, __float_as_int(x), 0x138, 0xF, 0xF, true));
}
static __device__ __forceinline__ int dpp_shr1_i(int x) {
    return __builtin_amdgcn_update_dpp(0, x, 0x138, 0xF, 0xF, true);
}
template <int CTRL>
static __device__ __forceinline__ float dpp_add(float x) {
    const int y = __builtin_amdgcn_update_dpp(0, __float_as_int(x), CTRL, 0xF, 0xF, true);
    return x + __int_as_float(y);
}

// One wave per (b,t) row, grid-strided 8 rows/wave.
__global__ __launch_bounds__(256) void ctc_prep(
    const float* __restrict__ x, const int* __restrict__ lens,
    const int* __restrict__ tgts)
{
    const int lane = threadIdx.x & 63;
    const int wv0  = (int)((blockIdx.x * blockDim.x + threadIdx.x) >> 6); // 0..8191
    const float L2E = 1.44269504088896340736f;

    #pragma unroll
    for (int it = 0; it < ROWS_PER_WAVE; ++it) {
        const int wid = wv0 + it * 8192;        // t preserved, b += 8 per iter
        const int b = wid >> 10;
        const int t = wid & (T_LEN - 1);
        if (t >= lens[b]) continue;             // frozen frames never read

        const float* row = x + (size_t)wid * V_DIM;
        const float4 u = *(const float4*)(row + lane * 8);
        const float4 v = *(const float4*)(row + lane * 8 + 4);

        float s = exp2f(u.x * L2E) + exp2f(u.y * L2E)
                + exp2f(u.z * L2E) + exp2f(u.w * L2E)
                + exp2f(v.x * L2E) + exp2f(v.y * L2E)
                + exp2f(v.z * L2E) + exp2f(v.w * L2E);
        s = dpp_add<0x111>(s);          // row_shr:1
        s = dpp_add<0x112>(s);          // row_shr:2
        s = dpp_add<0x114>(s);          // row_shr:4
        s = dpp_add<0x118>(s);          // row_shr:8
        s = dpp_add<0x142>(s);          // row_bcast:15
        s = dpp_add<0x143>(s);          // row_bcast:31 -> lane 63 has wave sum
        const float off =
            log2f(__int_as_float(__builtin_amdgcn_readlane(__float_as_int(s), 63)));

        if (lane == 0) g_pblank[wid] = exp2f(u.x * L2E - off);

        const int2 tg = *(const int2*)(tgts + b * S_LEN + 2 * lane);
        g_plab[(size_t)wid * 64 + lane] =
            make_float2(exp2f(row[tg.x] * L2E - off), exp2f(row[tg.y] * L2E - off));
    }
}

struct AlphaState { float a0, a1, a2, a3, a4; int C; };

// FULL step: dead-lane C adoption (t <= deadline phase). Bitwise = R10 proven.
static __device__ __forceinline__ void alpha_step(
    AlphaState& st, float pb, float2 lp, float cs1f, float cs3f, bool dead)
{
    const float p3 = dpp_shr1_f(st.a3);        // lane0 gets 0
    const int   Cp = dpp_shr1_i(st.C);
    const int   Cn = dead ? Cp : st.C;
    int e = 127 + (Cp - Cn);
    e = e < 0 ? 0 : (e > 252 ? 252 : e);
    const float adj = __int_as_float((unsigned)e << 23);
    const float p3v = p3 * adj;
    const float s01 = st.a0 + st.a1;
    const float s23 = st.a2 + st.a3;
    const float n0 = (st.a0 + p3v) * pb;
    const float n1 = fmaf(p3v, cs1f, s01) * lp.x;
    const float n2 = (st.a1 + st.a2) * pb;
    const float n3 = fmaf(st.a1, cs3f, s23) * lp.y;
    const float n4 = (st.a3 + st.a4) * pb;
    st.a0 = n0; st.a1 = n1; st.a2 = n2; st.a3 = n3; st.a4 = n4; st.C = Cn;
}

// LEAN step: all lanes live, adj hoisted (C constant within a 4-step window).
// Computes the exact same values as alpha_step with dead=false.
static __device__ __forceinline__ void lean_step(
    AlphaState& st, float pb, float2 lp, float cs1f, float cs3f, float adj)
{
    const float p3 = dpp_shr1_f(st.a3);
    const float p3v = p3 * adj;
    const float s01 = st.a0 + st.a1;
    const float s23 = st.a2 + st.a3;
    const float n0 = (st.a0 + p3v) * pb;
    const float n1 = fmaf(p3v, cs1f, s01) * lp.x;
    const float n2 = (st.a1 + st.a2) * pb;
    const float n3 = fmaf(st.a1, cs3f, s23) * lp.y;
    const float n4 = (st.a3 + st.a4) * pb;
    st.a0 = n0; st.a1 = n1; st.a2 = n2; st.a3 = n3; st.a4 = n4;
}

// R10-proven rescale: normalize lane max to ~1.0; exact power-of-2 bookkeeping.
static __device__ __forceinline__ void alpha_rescale(AlphaState& st)
{
    const float mx = fmaxf(fmaxf(fmaxf(st.a0, st.a1), fmaxf(st.a2, st.a3)), st.a4);
    const int ee = (__float_as_int(mx) >> 23) & 255;
    const bool ok = (ee > 0) && (ee < 255);
    const float sc = ok ? __int_as_float((unsigned)(254 - ee) << 23) : 1.0f;
    const int dC = ok ? (ee - 127) : 0;
    st.a0 *= sc; st.a1 *= sc; st.a2 *= sc; st.a3 *= sc; st.a4 *= sc; st.C += dC;
}

// Register-resident 8-step group (16 VGPRs). Compile-time-indexed (rule #20).
struct LG { float2 v[8]; };

// 8 plain global_load_dwordx2 straight to VGPRs (lane-coalesced rows).
static __device__ __forceinline__ void issue8(
    LG& L, const float2* __restrict__ pl_b, int tb, int lenm1, int lane)
{
    #pragma unroll
    for (int j = 0; j < 8; ++j) {
        int r = tb + j; r = (r < lenm1) ? r : lenm1;  // clamped rows never consumed
        L.v[j] = pl_b[(size_t)r * 64 + lane];
    }
}

// blank probs: ONE lane-indexed dword load covers the group's 8 uniform values;
// consumed via readlane(pb8, i) broadcast. 1 VGPR, 1 VMEM op, no LDS.
static __device__ __forceinline__ float pbr(float pb8, int i) {
    return __int_as_float(__builtin_amdgcn_readlane(__float_as_int(pb8), i));
}

template<bool LEAN>
static __device__ __forceinline__ void compute8(
    AlphaState& st, const LG& L, float pb8,
    float cs1f, float cs3f, int tb, int deadline)
{
    float adj = 1.0f;
    #pragma unroll
    for (int i = 0; i < 8; ++i) {
        if (LEAN) {
            if ((i & 3) == 0) {     // C constant until next rescale -> hoist adj
                const int Cp = dpp_shr1_i(st.C);
                int e = 127 + (Cp - st.C);
                e = e < 0 ? 0 : (e > 252 ? 252 : e);
                adj = __int_as_float((unsigned)e << 23);
            }
            lean_step(st, pbr(pb8, i), L.v[i], cs1f, cs3f, adj);
        } else {
            alpha_step(st, pbr(pb8, i), L.v[i], cs1f, cs3f, deadline >= tb + i);
        }
        if ((i & 3) == 3) alpha_rescale(st);
    }
}

#define WAIT9() do { __builtin_amdgcn_sched_barrier(0);  \
    __builtin_amdgcn_s_waitcnt(0x0F79); /* vmcnt(9) */   \
    __builtin_amdgcn_sched_barrier(0); } while (0)
#define WAIT0() do { __builtin_amdgcn_sched_barrier(0);  \
    __builtin_amdgcn_s_waitcnt(0x0F70); /* vmcnt(0) */   \
    __builtin_amdgcn_sched_barrier(0); } while (0)

// 16 waves/block, 4 blocks: 4 waves per SIMD hide the dependent-chain latency
// that paced rounds 3-5 (one wave/CU issued 1 VALU per ~11 cyc). Zero LDS;
// launch_bounds(1024) caps VGPR at 128 so the full block is resident.
__global__ __launch_bounds__(1024) void ctc_alpha(
    const int* __restrict__ lens, const int* __restrict__ tgts,
    const int* __restrict__ tlens, float* __restrict__ out)
{
    const int lane = threadIdx.x & 63;
    const int b    = (int)blockIdx.x * WPB + (int)(threadIdx.x >> 6);
    const int len  = lens[b];                   // wave-uniform
    const int tl   = tlens[b];
    const int lenm1 = len - 1;

    const int tA = tgts[b * S_LEN + 2 * lane];
    const int tB = tgts[b * S_LEN + 2 * lane + 1];
    const int tPrev = __shfl_up(tB, 1);
    const bool cs1 = (lane > 0) && (tA != tPrev);   // skip into state 4l+1
    const bool cs3 = (tB != tA);                    // skip into state 4l+3
    const float cs1f = cs1 ? 1.0f : 0.0f;
    const float cs3f = cs3 ? 1.0f : 0.0f;

    // Exact dead-lane deadline: state 4l first gets mass at tau = 2l + R_l.
    const int repOwn = ((lane > 0 && tA == tPrev) ? 1 : 0) + ((tB == tA) ? 1 : 0);
    int ps = repOwn;
    #pragma unroll
    for (int d = 1; d < 64; d <<= 1) {
        const int y = __shfl_up(ps, d);
        if (lane >= d) ps += y;
    }
    const int deadline = 2 * lane + (ps - repOwn);
    const int dmax = __shfl(deadline, 63);      // deadline increases with lane

    const size_t rowb = (size_t)b * T_LEN;
    const float*  __restrict__ pb_b = g_pblank + rowb;
    const float2* __restrict__ pl_b = g_plab + rowb * 64;

    AlphaState st;
    st.a0 = 0.f; st.a1 = 0.f; st.a2 = 0.f; st.a3 = 0.f; st.a4 = 0.f; st.C = 0;
    if (lane == 0) { st.a0 = pb_b[0]; st.a1 = pl_b[0].x; }

    LG LA, LB; float pbA, pbB;
    issue8(LA, pl_b, 1, lenm1, lane);           // group0: rows 1..8
    pbA = pb_b[1 + (lane & 7)];                 // pb(1..8), broadcast-served

    int t0 = 1;
    // 2 groups per iteration: named buffers, no runtime buffer index (rule #20).
    for (; t0 + 16 <= len; t0 += 16) {
        issue8(LB, pl_b, t0 + 8, lenm1, lane);  // next group flies (9 VMEM)
        pbB = pb_b[t0 + 8 + (lane & 7)];
        WAIT9();                                // cur 9 done; next 9 outstanding
        if (t0 > dmax) compute8<true >(st, LA, pbA, cs1f, cs3f, t0, deadline);
        else           compute8<false>(st, LA, pbA, cs1f, cs3f, t0, deadline);

        issue8(LA, pl_b, t0 + 16, lenm1, lane); // refill (pad covers overread)
        pbA = pb_b[t0 + 16 + (lane & 7)];
        WAIT9();
        if (t0 + 8 > dmax) compute8<true >(st, LB, pbB, cs1f, cs3f, t0 + 8, deadline);
        else               compute8<false>(st, LB, pbB, cs1f, cs3f, t0 + 8, deadline);
    }
    // tail: r = len - t0 in [0,16). LA holds rows t0..t0+7 (in flight).
    if (t0 + 8 < len) {                         // need rows t0+8..len-1 too
        issue8(LB, pl_b, t0 + 8, lenm1, lane);
        pbB = pb_b[t0 + 8 + (lane & 7)];
    }
    WAIT0();
    #pragma unroll
    for (int i = 0; i < 8; ++i) {
        if (t0 + i < len) {                     // wave-uniform bound
            alpha_step(st, pbr(pbA, i), LA.v[i], cs1f, cs3f, deadline >= t0 + i);
            if ((i & 3) == 3) alpha_rescale(st);
        }
    }
    #pragma unroll
    for (int i = 8; i < 16; ++i) {
        if (t0 + i < len) {
            alpha_step(st, pbr(pbB, i - 8), LB.v[i - 8], cs1f, cs3f,
                       deadline >= t0 + i);
            if ((i & 3) == 3) alpha_rescale(st);
        }
    }

    // terminal: states end = 2*tl and end-1 (end in [128,256])
    const int end = 2 * tl;
    float v1, v2; int C1, C2;
    {
        int s = end;
        int lsrc = s >> 2; if (lsrc > 63) lsrc = 63;
        const int slot = s & 3;
        float cand = (slot == 0) ? st.a0 : (slot == 1) ? st.a1
                   : (slot == 2) ? st.a2 : st.a3;
        if (s == 256) cand = st.a4;             // uniform; source lane 63's shadow
        v1 = __shfl(cand, lsrc);
        C1 = __shfl(st.C, lsrc);

        s = end - 1;
        lsrc = s >> 2;
        const int slot2 = s & 3;
        cand = (slot2 == 0) ? st.a0 : (slot2 == 1) ? st.a1
             : (slot2 == 2) ? st.a2 : st.a3;
        v2 = __shfl(cand, lsrc);
        C2 = __shfl(st.C, lsrc);
    }
    const float l1 = (v1 > 0.f) ? log2f(v1) + (float)C1 : NEG2;
    const float l2 = (v2 > 0.f) ? log2f(v2) + (float)C2 : NEG2;
    const float mM = fmaxf(l1, l2);
    const float ll2 = mM + log2f(exp2f(l1 - mM) + exp2f(l2 - mM));
    float loss = -ll2 * 0.69314718055994530942f;
    if (!(loss < 1e29f)) loss = 0.f;            // zero_infinity (+NaN guard)
    if (lane == 0) atomicAdd(out, loss);
}

extern "C" void kernel_launch(void* const* d_in, const int* in_sizes, int n_in,
                              void* d_out, int out_size, void* d_ws, size_t ws_size,
                              hipStream_t stream) {
    (void)in_sizes; (void)n_in; (void)d_ws; (void)ws_size;
    const float* x     = (const float*)d_in[0];   // [64,1024,512] f32
    const int*   lens  = (const int*)d_in[1];     // [64]
    const int*   tgts  = (const int*)d_in[2];     // [64,128]
    const int*   tlens = (const int*)d_in[3];     // [64]
    float* out = (float*)d_out;

    (void)hipMemsetAsync(d_out, 0, (size_t)out_size * sizeof(float), stream);
    ctc_prep<<<PREP_BLOCKS, 256, 0, stream>>>(x, lens, tgts);
    ctc_alpha<<<ALPHA_BLOCKS, WPB * 64, 0, stream>>>(lens, tgts, tlens, out);
}

// Round 7
// 250.548 us; speedup vs baseline: 1.4034x; 1.4034x over previous
//
#include <hip/hip_runtime.h>
#include <cstdint>

#define T_LEN 1024
#define V_DIM 512
#define S_LEN 128
#define NEG2  (-1.0e30f)
#define PREP_BLOCKS 2048  // grid-stride prep
#define ROWS_PER_WAVE 8   // 65536 rows / (2048 blk * 4 waves)

// Staging: LINEAR probabilities of the needed classes per (b,t).
// g_plab pad = 64 full rows (4096 float2): unclamped prefetch may over-read up
// to 31 rows past len for the last batch; garbage is never consumed.
__device__ float2 g_plab[(size_t)64 * T_LEN * 64 + 4096];  // 32 MiB + 32 KiB pad
__device__ float  g_pblank[(size_t)64 * T_LEN + 64];       // 256 KiB: blank (+pad)

// whole-wave shift-down-by-1 via DPP wave_shr1: lane l <- lane l-1, lane 0 <- 0.
static __device__ __forceinline__ float dpp_shr1_f(float x) {
    return __int_as_float(__builtin_amdgcn_update_dpp(
        0, __float_as_int(x), 0x138, 0xF, 0xF, true));
}
static __device__ __forceinline__ int dpp_shr1_i(int x) {
    return __builtin_amdgcn_update_dpp(0, x, 0x138, 0xF, 0xF, true);
}
template <int CTRL>
static __device__ __forceinline__ float dpp_add(float x) {
    const int y = __builtin_amdgcn_update_dpp(0, __float_as_int(x), CTRL, 0xF, 0xF, true);
    return x + __int_as_float(y);
}

// One wave per (b,t) row, grid-strided 8 rows/wave.
__global__ __launch_bounds__(256) void ctc_prep(
    const float* __restrict__ x, const int* __restrict__ lens,
    const int* __restrict__ tgts)
{
    const int lane = threadIdx.x & 63;
    const int wv0  = (int)((blockIdx.x * blockDim.x + threadIdx.x) >> 6); // 0..8191
    const float L2E = 1.44269504088896340736f;

    #pragma unroll
    for (int it = 0; it < ROWS_PER_WAVE; ++it) {
        const int wid = wv0 + it * 8192;        // t preserved, b += 8 per iter
        const int b = wid >> 10;
        const int t = wid & (T_LEN - 1);
        if (t >= lens[b]) continue;             // frozen frames never read

        const float* row = x + (size_t)wid * V_DIM;
        const float4 u = *(const float4*)(row + lane * 8);
        const float4 v = *(const float4*)(row + lane * 8 + 4);

        float s = exp2f(u.x * L2E) + exp2f(u.y * L2E)
                + exp2f(u.z * L2E) + exp2f(u.w * L2E)
                + exp2f(v.x * L2E) + exp2f(v.y * L2E)
                + exp2f(v.z * L2E) + exp2f(v.w * L2E);
        s = dpp_add<0x111>(s);          // row_shr:1
        s = dpp_add<0x112>(s);          // row_shr:2
        s = dpp_add<0x114>(s);          // row_shr:4
        s = dpp_add<0x118>(s);          // row_shr:8
        s = dpp_add<0x142>(s);          // row_bcast:15
        s = dpp_add<0x143>(s);          // row_bcast:31 -> lane 63 has wave sum
        const float off =
            log2f(__int_as_float(__builtin_amdgcn_readlane(__float_as_int(s), 63)));

        if (lane == 0) g_pblank[wid] = exp2f(u.x * L2E - off);

        const int2 tg = *(const int2*)(tgts + b * S_LEN + 2 * lane);
        g_plab[(size_t)wid * 64 + lane] =
            make_float2(exp2f(row[tg.x] * L2E - off), exp2f(row[tg.y] * L2E - off));
    }
}

struct AlphaState { float a0, a1, a2, a3, a4; int C; };

// FULL step: dead-lane C adoption (t <= deadline phase). Bitwise = R10 proven.
static __device__ __forceinline__ void alpha_step(
    AlphaState& st, float pb, float2 lp, float cs1f, float cs3f, bool dead)
{
    const float p3 = dpp_shr1_f(st.a3);        // lane0 gets 0
    const int   Cp = dpp_shr1_i(st.C);
    const int   Cn = dead ? Cp : st.C;
    int e = 127 + (Cp - Cn);
    e = e < 0 ? 0 : (e > 252 ? 252 : e);
    const float adj = __int_as_float((unsigned)e << 23);
    const float p3v = p3 * adj;
    const float s01 = st.a0 + st.a1;
    const float s23 = st.a2 + st.a3;
    const float n0 = (st.a0 + p3v) * pb;
    const float n1 = fmaf(p3v, cs1f, s01) * lp.x;
    const float n2 = (st.a1 + st.a2) * pb;
    const float n3 = fmaf(st.a1, cs3f, s23) * lp.y;
    const float n4 = (st.a3 + st.a4) * pb;
    st.a0 = n0; st.a1 = n1; st.a2 = n2; st.a3 = n3; st.a4 = n4; st.C = Cn;
}

// LEAN step: all lanes live, adj hoisted (C constant within a 4-step window).
static __device__ __forceinline__ void lean_step(
    AlphaState& st, float pb, float2 lp, float cs1f, float cs3f, float adj)
{
    const float p3 = dpp_shr1_f(st.a3);
    const float p3v = p3 * adj;
    const float s01 = st.a0 + st.a1;
    const float s23 = st.a2 + st.a3;
    const float n0 = (st.a0 + p3v) * pb;
    const float n1 = fmaf(p3v, cs1f, s01) * lp.x;
    const float n2 = (st.a1 + st.a2) * pb;
    const float n3 = fmaf(st.a1, cs3f, s23) * lp.y;
    const float n4 = (st.a3 + st.a4) * pb;
    st.a0 = n0; st.a1 = n1; st.a2 = n2; st.a3 = n3; st.a4 = n4;
}

// R10-proven rescale: normalize lane max to ~1.0; exact power-of-2 bookkeeping.
static __device__ __forceinline__ void alpha_rescale(AlphaState& st)
{
    const float mx = fmaxf(fmaxf(fmaxf(st.a0, st.a1), fmaxf(st.a2, st.a3)), st.a4);
    const int ee = (__float_as_int(mx) >> 23) & 255;
    const bool ok = (ee > 0) && (ee < 255);
    const float sc = ok ? __int_as_float((unsigned)(254 - ee) << 23) : 1.0f;
    const int dC = ok ? (ee - 127) : 0;
    st.a0 *= sc; st.a1 *= sc; st.a2 *= sc; st.a3 *= sc; st.a4 *= sc; st.C += dC;
}

// Register-resident 16-step group. All accesses compile-time-indexed (rule #20).
struct LGrp  { float2 v[16]; };           // labels: 32 VGPRs
struct PBGrp { float4 a, b, c, d; };      // blanks: 16 VGPRs

static __device__ __forceinline__ float pbsel(const PBGrp& p, int i) {
    // i is const-folded after unroll -> pure register select
    const float4 q = (i < 4) ? p.a : (i < 8) ? p.b : (i < 12) ? p.c : p.d;
    const int m = i & 3;
    return m == 0 ? q.x : m == 1 ? q.y : m == 2 ? q.z : q.w;
}

// 16 plain global_load_dwordx2 straight to VGPRs, UNCLAMPED: one base address,
// 15 immediate offsets (j*512B fits the 13-bit signed imm). Over-read rows
// (>= len) land in the 64-row pad and are never consumed.
static __device__ __forceinline__ void issueL(
    LGrp& L, const float2* __restrict__ pl_b, int tb, int lane)
{
    const float2* p = pl_b + (size_t)tb * 64 + lane;
    #pragma unroll
    for (int j = 0; j < 16; ++j) L.v[j] = p[j * 64];
}

static __device__ __forceinline__ void loadPB(PBGrp& P, const float* s) {
    P.a = *(const float4*)(s);
    P.b = *(const float4*)(s + 4);
    P.c = *(const float4*)(s + 8);
    P.d = *(const float4*)(s + 12);
}

template<bool LEAN>
static __device__ __forceinline__ void computeG16(
    AlphaState& st, const LGrp& L, const PBGrp& P,
    float cs1f, float cs3f, int tb, int deadline)
{
    float adj = 1.0f;
    #pragma unroll
    for (int i = 0; i < 16; ++i) {
        if (LEAN) {
            if ((i & 3) == 0) {     // C constant until next rescale -> hoist adj
                const int Cp = dpp_shr1_i(st.C);
                int e = 127 + (Cp - st.C);
                e = e < 0 ? 0 : (e > 252 ? 252 : e);
                adj = __int_as_float((unsigned)e << 23);
            }
            lean_step(st, pbsel(P, i), L.v[i], cs1f, cs3f, adj);
        } else {
            alpha_step(st, pbsel(P, i), L.v[i], cs1f, cs3f, deadline >= tb + i);
        }
        if ((i & 3) == 3) alpha_rescale(st);
    }
}

// tail (<16 steps): wave-uniform bounds; static indices via unroll.
static __device__ __forceinline__ void tail_steps(
    AlphaState& st, const LGrp& L, const PBGrp& P,
    float cs1f, float cs3f, int t0, int len, int deadline)
{
    #pragma unroll
    for (int i = 0; i < 15; ++i) {
        if (t0 + i < len) {
            alpha_step(st, pbsel(P, i), L.v[i], cs1f, cs3f, deadline >= t0 + i);
            if ((i & 3) == 3) alpha_rescale(st);
        }
    }
}

#define WAIT16() do { __builtin_amdgcn_sched_barrier(0);  \
    __builtin_amdgcn_s_waitcnt(0x4F70); /* vmcnt(16) */   \
    __builtin_amdgcn_sched_barrier(0); } while (0)

// One wave per batch element (64 blocks = 64 CUs; latency-bound serial DP).
// Register double-buffer: issue group k+1's 16 global loads (aged one full
// group ~3000 cyc >> HBM latency), compute group k from VGPRs.
__global__ __launch_bounds__(64) void ctc_alpha(
    const int* __restrict__ lens, const int* __restrict__ tgts,
    const int* __restrict__ tlens, float* __restrict__ out)
{
    __shared__ alignas(16) float lds_pbs[T_LEN + 48];  // pb(t=i+1) at slot i; +48:
                                                       // next-group prefetch overreads

    const int b    = blockIdx.x;
    const int lane = threadIdx.x;
    const int len  = lens[b];                   // wave-uniform
    const int tl   = tlens[b];

    const int tA = tgts[b * S_LEN + 2 * lane];
    const int tB = tgts[b * S_LEN + 2 * lane + 1];
    const int tPrev = __shfl_up(tB, 1);
    const bool cs1 = (lane > 0) && (tA != tPrev);   // skip into state 4l+1
    const bool cs3 = (tB != tA);                    // skip into state 4l+3
    const float cs1f = cs1 ? 1.0f : 0.0f;
    const float cs3f = cs3 ? 1.0f : 0.0f;

    // Exact dead-lane deadline: state 4l first gets mass at tau = 2l + R_l.
    const int repOwn = ((lane > 0 && tA == tPrev) ? 1 : 0) + ((tB == tA) ? 1 : 0);
    int ps = repOwn;
    #pragma unroll
    for (int d = 1; d < 64; d <<= 1) {
        const int y = __shfl_up(ps, d);
        if (lane >= d) ps += y;
    }
    const int deadline = 2 * lane + (ps - repOwn);
    const int dmax = __shfl(deadline, 63);      // deadline increases with lane

    const size_t rowb = (size_t)b * T_LEN;
    const float*  __restrict__ pb_b = g_pblank + rowb;
    const float2* __restrict__ pl_b = g_plab + rowb * 64;

    // blank table, shifted by -1: slot i holds pb(t=i+1) (+64 global pad).
    #pragma unroll
    for (int k = 0; k < T_LEN / 64; ++k)
        lds_pbs[k * 64 + lane] = pb_b[k * 64 + lane + 1];

    AlphaState st;
    st.a0 = 0.f; st.a1 = 0.f; st.a2 = 0.f; st.a3 = 0.f; st.a4 = 0.f; st.C = 0;
    if (lane == 0) { st.a0 = pb_b[0]; st.a1 = pl_b[0].x; }

    LGrp LA, LB; PBGrp PA, PB_;
    issueL(LA, pl_b, 1, lane);                  // group0: rows 1..16
    loadPB(PA, &lds_pbs[0]);

    int t0 = 1;
    // 2 groups per iteration: named buffers, no runtime buffer index (rule #20).
    for (; t0 + 32 <= len; t0 += 32) {
        issueL(LB, pl_b, t0 + 16, lane);        // next group's labels fly
        loadPB(PB_, &lds_pbs[t0 + 15]);         // next group's blanks fly (lgkm)
        WAIT16();                               // cur 16 done; next 16 outstanding
        if (t0 > dmax) computeG16<true >(st, LA, PA, cs1f, cs3f, t0, deadline);
        else           computeG16<false>(st, LA, PA, cs1f, cs3f, t0, deadline);

        issueL(LA, pl_b, t0 + 32, lane);        // refill (pad covers overread)
        loadPB(PA, &lds_pbs[t0 + 31]);
        WAIT16();
        if (t0 + 16 > dmax) computeG16<true >(st, LB, PB_, cs1f, cs3f, t0 + 16, deadline);
        else                computeG16<false>(st, LB, PB_, cs1f, cs3f, t0 + 16, deadline);
    }
    if (t0 + 16 <= len) {                       // one full group + tail
        issueL(LB, pl_b, t0 + 16, lane);
        loadPB(PB_, &lds_pbs[t0 + 15]);
        WAIT16();
        if (t0 > dmax) computeG16<true >(st, LA, PA, cs1f, cs3f, t0, deadline);
        else           computeG16<false>(st, LA, PA, cs1f, cs3f, t0, deadline);
        t0 += 16;
        __builtin_amdgcn_s_waitcnt(0x0F70);     // vmcnt(0)
        __builtin_amdgcn_sched_barrier(0);
        tail_steps(st, LB, PB_, cs1f, cs3f, t0, len, deadline);
    } else {                                    // tail only
        __builtin_amdgcn_s_waitcnt(0x0F70);     // vmcnt(0)
        __builtin_amdgcn_sched_barrier(0);
        tail_steps(st, LA, PA, cs1f, cs3f, t0, len, deadline);
    }

    // terminal: states end = 2*tl and end-1 (end in [128,256])
    const int end = 2 * tl;
    float v1, v2; int C1, C2;
    {
        int s = end;
        int lsrc = s >> 2; if (lsrc > 63) lsrc = 63;
        const int slot = s & 3;
        float cand = (slot == 0) ? st.a0 : (slot == 1) ? st.a1
                   : (slot == 2) ? st.a2 : st.a3;
        if (s == 256) cand = st.a4;             // uniform; source lane 63's shadow
        v1 = __shfl(cand, lsrc);
        C1 = __shfl(st.C, lsrc);

        s = end - 1;
        lsrc = s >> 2;
        const int slot2 = s & 3;
        cand = (slot2 == 0) ? st.a0 : (slot2 == 1) ? st.a1
             : (slot2 == 2) ? st.a2 : st.a3;
        v2 = __shfl(cand, lsrc);
        C2 = __shfl(st.C, lsrc);
    }
    const float l1 = (v1 > 0.f) ? log2f(v1) + (float)C1 : NEG2;
    const float l2 = (v2 > 0.f) ? log2f(v2) + (float)C2 : NEG2;
    const float mM = fmaxf(l1, l2);
    const float ll2 = mM + log2f(exp2f(l1 - mM) + exp2f(l2 - mM));
    float loss = -ll2 * 0.69314718055994530942f;
    if (!(loss < 1e29f)) loss = 0.f;            // zero_infinity (+NaN guard)
    if (lane == 0) atomicAdd(out, loss);
}

extern "C" void kernel_launch(void* const* d_in, const int* in_sizes, int n_in,
                              void* d_out, int out_size, void* d_ws, size_t ws_size,
                              hipStream_t stream) {
    (void)in_sizes; (void)n_in; (void)d_ws; (void)ws_size;
    const float* x     = (const float*)d_in[0];   // [64,1024,512] f32
    const int*   lens  = (const int*)d_in[1];     // [64]
    const int*   tgts  = (const int*)d_in[2];     // [64,128]
    const int*   tlens = (const int*)d_in[3];     // [64]
    float* out = (float*)d_out;

    (void)hipMemsetAsync(d_out, 0, (size_t)out_size * sizeof(float), stream);
    ctc_prep<<<PREP_BLOCKS, 256, 0, stream>>>(x, lens, tgts);
    ctc_alpha<<<64, 64, 0, stream>>>(lens, tgts, tlens, out);
}